// Round 3
// baseline (252.325 us; speedup 1.0000x reference)
//
#include <hip/hip_runtime.h>

// x:  [N=4, C=256, H=56, W=56] fp32
// w1: [N, 1, 32, 9,  H, W]     (3x3, pad 1)
// w2: [N, 1, 32, 25, H, W]     (5x5, pad 2)
// out:[N, 2, 1, C, H, W]
// out[n,b,c,h,w] = sum_p wB[n, c%32, p, h, w] * x[n, c, h+dh, w+dw] (zero pad)
//
// Thread = (n, v, gh in 0..3, 4-pixel strip). Each thread computes 4 consecutive
// pixels (float4) for 2 channel groups {2gh, 2gh+1}, both branches.
// All global loads are 16B-aligned float4. VGPR kept <=128 via launch_bounds
// so 4 waves/SIMD (16/CU) stay resident — round 2 collapsed to 2/SIMD @ 224 VGPR.

#define N_   4
#define C_   256
#define H_   56
#define W_   56
#define HW_  3136
#define WC_  32
#define W4_  14      // float4 chunks per row
#define HW4_ 784     // float4 chunks per plane

__global__ __launch_bounds__(256, 4) void lconv_kernel(
    const float* __restrict__ x,
    const float* __restrict__ w1,
    const float* __restrict__ w2,
    float* __restrict__ out)
{
    const int gid  = blockIdx.x * 256 + threadIdx.x;  // 0 .. 401407
    const int hw4  = gid % HW4_;
    const int rest = gid / HW4_;
    const int gh   = rest % 4;          // group pair: channels {2gh, 2gh+1}*32 + v
    const int v    = (rest / 4) % WC_;
    const int n    = rest / (4 * WC_);
    const int h    = hw4 / W4_;
    const int w4   = (hw4 % W4_) * 4;   // 0,4,...,52
    const int hw   = h * W_ + w4;
    const int nv   = n * WC_ + v;

    const float* w1t = w1 + (size_t)nv * 9  * HW_ + hw;
    const float* w2t = w2 + (size_t)nv * 25 * HW_ + hw;
    const int c0 = (2 * gh) * WC_ + v;                       // first group's channel
    const float* xb = x + ((size_t)n * C_ + c0) * HW_ + hw;  // +32*HW_ for 2nd group

    float a1[2][4], a2[2][4];
    #pragma unroll
    for (int g = 0; g < 2; ++g)
        #pragma unroll
        for (int p = 0; p < 4; ++p) { a1[g][p] = 0.f; a2[g][p] = 0.f; }

    const bool aok = (w4 > 0);        // left float4 chunk in-row
    const bool cok = (w4 < W_ - 4);   // right float4 chunk in-row

    #pragma unroll
    for (int di = 0; di < 5; ++di) {
        const int hh = h + di - 2;
        const bool hok = (hh >= 0) && (hh < H_);
        const bool inner = (di >= 1) && (di <= 3);

        // Per-pixel weight rows (float4 = weights for the 4 output pixels).
        float wr2[5][4];
        #pragma unroll
        for (int dj = 0; dj < 5; ++dj) {
            const float4 t = *(const float4*)(w2t + (size_t)(di * 5 + dj) * HW_);
            wr2[dj][0] = t.x; wr2[dj][1] = t.y; wr2[dj][2] = t.z; wr2[dj][3] = t.w;
        }
        float wr1[3][4];
        if (inner) {
            #pragma unroll
            for (int dj = 0; dj < 3; ++dj) {
                const float4 t = *(const float4*)(w1t + (size_t)((di - 1) * 3 + dj) * HW_);
                wr1[dj][0] = t.x; wr1[dj][1] = t.y; wr1[dj][2] = t.z; wr1[dj][3] = t.w;
            }
        }

        const int rowoff = (di - 2) * W_;
        #pragma unroll
        for (int g = 0; g < 2; ++g) {
            const float* xr = xb + (size_t)g * WC_ * HW_ + rowoff;
            const float4 z = make_float4(0.f, 0.f, 0.f, 0.f);
            const float4 xa = (hok && aok) ? *(const float4*)(xr - 4) : z;
            const float4 xm =  hok         ? *(const float4*)(xr)     : z;
            const float4 xc = (hok && cok) ? *(const float4*)(xr + 4) : z;
            // xw spans columns w4-4 .. w4+7
            const float xw[12] = {xa.x, xa.y, xa.z, xa.w,
                                  xm.x, xm.y, xm.z, xm.w,
                                  xc.x, xc.y, xc.z, xc.w};

            #pragma unroll
            for (int dj = 0; dj < 5; ++dj)
                #pragma unroll
                for (int p = 0; p < 4; ++p)
                    a2[g][p] += wr2[dj][p] * xw[p + dj + 2];
            if (inner) {
                #pragma unroll
                for (int dj = 0; dj < 3; ++dj)
                    #pragma unroll
                    for (int p = 0; p < 4; ++p)
                        a1[g][p] += wr1[dj][p] * xw[p + dj + 3];
            }
        }
    }

    float* o1 = out + ((size_t)(n * 2 + 0) * C_ + c0) * HW_ + hw;
    float* o2 = out + ((size_t)(n * 2 + 1) * C_ + c0) * HW_ + hw;
    #pragma unroll
    for (int g = 0; g < 2; ++g) {
        *(float4*)(o1 + (size_t)g * WC_ * HW_) =
            make_float4(a1[g][0], a1[g][1], a1[g][2], a1[g][3]);
        *(float4*)(o2 + (size_t)g * WC_ * HW_) =
            make_float4(a2[g][0], a2[g][1], a2[g][2], a2[g][3]);
    }
}

extern "C" void kernel_launch(void* const* d_in, const int* in_sizes, int n_in,
                              void* d_out, int out_size, void* d_ws, size_t ws_size,
                              hipStream_t stream) {
    const float* x  = (const float*)d_in[0];
    const float* w1 = (const float*)d_in[1];
    const float* w2 = (const float*)d_in[2];
    float* out = (float*)d_out;

    const int total = N_ * WC_ * 4 * HW4_;      // 401408 threads
    dim3 grid(total / 256), block(256);
    hipLaunchKernelGGL(lconv_kernel, grid, block, 0, stream, x, w1, w2, out);
}

// Round 4
// 139.837 us; speedup vs baseline: 1.8044x; 1.8044x over previous
//
#include <hip/hip_runtime.h>

// x:  [N=4, C=256, H=56, W=56] fp32
// w1: [N, 1, 32, 9,  H, W]     (3x3, pad 1)
// w2: [N, 1, 32, 25, H, W]     (5x5, pad 2)
// out:[N, 2, 1, C, H, W]
// out[n,b,c,h,w] = sum_p wB[n, c%32, p, h, w] * x[n, c, h+dh, w+dw] (zero pad)
//
// Thread = (n, v, 2-pixel float2 strip, gh in 0..3). gh is the LOWEST gid bits
// so the 4 threads sharing one pixel's weights are adjacent lanes -> their
// identical weight loads merge in L1 (R3 put them ~3 blocks apart -> 4x HBM
// weight refetch). Each thread: 2 channel groups {2gh, 2gh+1}, both branches.
// acc = 8 regs. di loop is unroll-1 to stop the compiler hoisting all 34
// weight rows (R2: 224 VGPR -> 2 waves/SIMD). NO forced launch_bounds cap:
// R3's (256,4) forced spills (WRITE_SIZE 276 MB vs 25.7 MB real output).

#define N_   4
#define C_   256
#define H_   56
#define W_   56
#define HW_  3136
#define WC_  32
#define W2_  28      // float2 columns per row
#define HW2_ 1568    // float2 positions per plane

__global__ __launch_bounds__(256) void lconv_kernel(
    const float* __restrict__ x,
    const float* __restrict__ w1,
    const float* __restrict__ w2,
    float* __restrict__ out)
{
    const int gid = blockIdx.x * 256 + threadIdx.x;   // 0 .. 802815
    const int gh  = gid & 3;          // group pair {2gh, 2gh+1}
    const int t   = gid >> 2;
    const int hw2 = t % HW2_;
    const int nv  = t / HW2_;         // n*32 + v
    const int v   = nv & 31;
    const int n   = nv >> 5;
    const int h   = hw2 / W2_;
    const int wb  = (hw2 % W2_) * 2;  // 0..54 even
    const int hw  = h * W_ + wb;

    const float* w1t = w1 + (size_t)nv * 9  * HW_ + hw;
    const float* w2t = w2 + (size_t)nv * 25 * HW_ + hw;
    const int c0 = gh * 64 + v;                              // first group's channel
    const float* xb = x + ((size_t)n * C_ + c0) * HW_ + hw;  // +32*HW_ for 2nd group

    float a1x[2] = {0.f, 0.f}, a1y[2] = {0.f, 0.f};
    float a2x[2] = {0.f, 0.f}, a2y[2] = {0.f, 0.f};

    const bool aok = (wb > 0);        // left float2 chunk in-row
    const bool cok = (wb < W_ - 2);   // right float2 chunk in-row

    #pragma unroll 1
    for (int di = 0; di < 5; ++di) {
        const int hh = h + di - 2;
        const bool hok = (hh >= 0) && (hh < H_);
        const bool inner = (di >= 1) && (di <= 3);

        // Per-pixel weight rows: identical address across the 4 gh lanes.
        float2 wr2[5];
        #pragma unroll
        for (int dj = 0; dj < 5; ++dj)
            wr2[dj] = *(const float2*)(w2t + (size_t)(di * 5 + dj) * HW_);
        float2 wr1[3];
        #pragma unroll
        for (int dj = 0; dj < 3; ++dj)
            wr1[dj] = make_float2(0.f, 0.f);
        if (inner) {
            #pragma unroll
            for (int dj = 0; dj < 3; ++dj)
                wr1[dj] = *(const float2*)(w1t + (size_t)((di - 1) * 3 + dj) * HW_);
        }

        const int rowoff = (di - 2) * W_;
        #pragma unroll
        for (int g = 0; g < 2; ++g) {
            const float* xr = xb + (size_t)g * WC_ * HW_ + rowoff;
            const float2 z = make_float2(0.f, 0.f);
            const float2 xa = (hok && aok) ? *(const float2*)(xr - 2) : z;
            const float2 xm =  hok         ? *(const float2*)(xr)     : z;
            const float2 xc = (hok && cok) ? *(const float2*)(xr + 2) : z;
            const float xw[6] = {xa.x, xa.y, xm.x, xm.y, xc.x, xc.y};

            #pragma unroll
            for (int dj = 0; dj < 5; ++dj) {
                a2x[g] += wr2[dj].x * xw[dj];
                a2y[g] += wr2[dj].y * xw[dj + 1];
            }
            #pragma unroll
            for (int dj = 0; dj < 3; ++dj) {
                a1x[g] += wr1[dj].x * xw[dj + 1];
                a1y[g] += wr1[dj].y * xw[dj + 2];
            }
        }
    }

    float* o1 = out + ((size_t)(n * 2 + 0) * C_ + c0) * HW_ + hw;
    float* o2 = out + ((size_t)(n * 2 + 1) * C_ + c0) * HW_ + hw;
    #pragma unroll
    for (int g = 0; g < 2; ++g) {
        *(float2*)(o1 + (size_t)g * WC_ * HW_) = make_float2(a1x[g], a1y[g]);
        *(float2*)(o2 + (size_t)g * WC_ * HW_) = make_float2(a2x[g], a2y[g]);
    }
}

extern "C" void kernel_launch(void* const* d_in, const int* in_sizes, int n_in,
                              void* d_out, int out_size, void* d_ws, size_t ws_size,
                              hipStream_t stream) {
    const float* x  = (const float*)d_in[0];
    const float* w1 = (const float*)d_in[1];
    const float* w2 = (const float*)d_in[2];
    float* out = (float*)d_out;

    const int total = N_ * WC_ * HW2_ * 4;      // 802816 threads
    dim3 grid(total / 256), block(256);
    hipLaunchKernelGGL(lconv_kernel, grid, block, 0, stream, x, w1, w2, out);
}

// Round 5
// 112.777 us; speedup vs baseline: 2.2374x; 1.2399x over previous
//
#include <hip/hip_runtime.h>

// x:  [N=4, C=256, H=56, W=56] fp32
// w1: [N, 1, 32, 9,  H, W]     (3x3, pad 1)
// w2: [N, 1, 32, 25, H, W]     (5x5, pad 2)
// out:[N, 2, 1, C, H, W]
// out[n,b,c,h,w] = sum_p wB[n, c%32, p, h, w] * x[n, c, h+dh, w+dw] (zero pad)
//
// R5: LDS-staged x. Block = (n, v, gsel, 8-row tile) -> 1792 blocks = exactly
// 7/CU. Stage 4 x planes x 12 rows (+-2 halo) x 56 cols (12 KB LDS, zeroed
// halos). Thread = (row, float2 px strip) x 4 groups: 34 float2 weight loads
// (the compulsory HBM stream), 60 ds_read_b64 for x, 272 FMA. Global VMEM in
// the K-loop is weights only; x tap-reuse (34x) is serviced by LDS instead of
// L1 round-trips (R4: 60 us with VALU 12% / HBM 15% — issue+latency bound).

#define N_  4
#define C_  256
#define H_  56
#define W_  56
#define HW_ 3136
#define WC_ 32

#define LROWS   12
#define LSTRIDE 64   // slot s = x col (s-4); slots 2..3 and 60..61 are zero halo

__global__ __launch_bounds__(256) void lconv_kernel(
    const float* __restrict__ x,
    const float* __restrict__ w1,
    const float* __restrict__ w2,
    float* __restrict__ out)
{
    __shared__ float lds[4 * LROWS * LSTRIDE];   // 12 KB

    const int b    = blockIdx.x;      // 0..1791
    const int tile = b % 7;
    const int gsel = (b / 7) & 1;
    const int v    = (b / 14) & 31;
    const int n    = b / 448;
    const int r0   = tile * 8;
    const int nv   = n * WC_ + v;
    const int tid  = threadIdx.x;

    // ---- stage x: 4 planes x 12 rows x 56 cols as float4; zero OOB rows ----
    for (int idx = tid; idx < 672; idx += 256) {
        const int c4 = idx % 14;
        const int t2 = idx / 14;
        const int lr = t2 % LROWS;
        const int pl = t2 / LROWS;
        const int gr = r0 - 2 + lr;
        float4 val = make_float4(0.f, 0.f, 0.f, 0.f);
        if (gr >= 0 && gr < H_) {
            const int ch = gsel * 128 + pl * 32 + v;
            val = *(const float4*)(x + (size_t)(n * C_ + ch) * HW_ + gr * W_ + c4 * 4);
        }
        *(float4*)&lds[(pl * LROWS + lr) * LSTRIDE + 4 + c4 * 4] = val;
    }
    // zero the column halos: slots {2,3} (x cols -2,-1), {60,61} (x cols 56,57)
    if (tid < 192) {
        const int pl = tid / 48;
        const int lr = (tid % 48) / 4;
        const int k  = tid & 3;
        const int slot = (k < 2) ? (2 + k) : (58 + k);   // 2,3,60,61
        lds[(pl * LROWS + lr) * LSTRIDE + slot] = 0.f;
    }
    __syncthreads();

    const int row = tid >> 5;    // 0..7
    const int cp  = tid & 31;    // 0..31; only cp<28 compute
    if (cp >= 28) return;        // no barriers after this point

    const int h  = r0 + row;
    const int wb = cp * 2;
    const int hw = h * W_ + wb;

    const float* w1t = w1 + (size_t)nv * 9  * HW_ + hw;
    const float* w2t = w2 + (size_t)nv * 25 * HW_ + hw;

    float a1x[4] = {0.f,0.f,0.f,0.f}, a1y[4] = {0.f,0.f,0.f,0.f};
    float a2x[4] = {0.f,0.f,0.f,0.f}, a2y[4] = {0.f,0.f,0.f,0.f};

    #pragma unroll 1
    for (int di = 0; di < 5; ++di) {
        const bool inner = (di >= 1) && (di <= 3);

        // weight rows for this di (the only global loads in the loop)
        float2 wr2[5];
        #pragma unroll
        for (int dj = 0; dj < 5; ++dj)
            wr2[dj] = *(const float2*)(w2t + (size_t)(di * 5 + dj) * HW_);
        float2 wr1[3] = {make_float2(0.f,0.f), make_float2(0.f,0.f), make_float2(0.f,0.f)};
        if (inner) {
            #pragma unroll
            for (int dj = 0; dj < 3; ++dj)
                wr1[dj] = *(const float2*)(w1t + (size_t)((di - 1) * 3 + dj) * HW_);
        }

        // x windows from LDS: slots wb+2 .. wb+7 per group (x cols wb-2..wb+3)
        float2 xwa[4], xwb[4], xwc[4];
        #pragma unroll
        for (int j = 0; j < 4; ++j) {
            const float* lp = &lds[(j * LROWS + row + di) * LSTRIDE + wb + 2];
            xwa[j] = *(const float2*)(lp);
            xwb[j] = *(const float2*)(lp + 2);
            xwc[j] = *(const float2*)(lp + 4);
        }

        #pragma unroll
        for (int j = 0; j < 4; ++j) {
            const float xw[6] = {xwa[j].x, xwa[j].y, xwb[j].x, xwb[j].y, xwc[j].x, xwc[j].y};
            #pragma unroll
            for (int dj = 0; dj < 5; ++dj) {
                a2x[j] += wr2[dj].x * xw[dj];
                a2y[j] += wr2[dj].y * xw[dj + 1];
            }
            if (inner) {
                #pragma unroll
                for (int dj = 0; dj < 3; ++dj) {
                    a1x[j] += wr1[dj].x * xw[dj + 1];
                    a1y[j] += wr1[dj].y * xw[dj + 2];
                }
            }
        }
    }

    const int c0 = gsel * 128 + v;
    float* o1 = out + ((size_t)(n * 2 + 0) * C_ + c0) * HW_ + hw;
    float* o2 = out + ((size_t)(n * 2 + 1) * C_ + c0) * HW_ + hw;
    #pragma unroll
    for (int j = 0; j < 4; ++j) {
        *(float2*)(o1 + (size_t)j * WC_ * HW_) = make_float2(a1x[j], a1y[j]);
        *(float2*)(o2 + (size_t)j * WC_ * HW_) = make_float2(a2x[j], a2y[j]);
    }
}

extern "C" void kernel_launch(void* const* d_in, const int* in_sizes, int n_in,
                              void* d_out, int out_size, void* d_ws, size_t ws_size,
                              hipStream_t stream) {
    const float* x  = (const float*)d_in[0];
    const float* w1 = (const float*)d_in[1];
    const float* w2 = (const float*)d_in[2];
    float* out = (float*)d_out;

    dim3 grid(4 * 32 * 2 * 7), block(256);   // 1792 blocks = 7/CU exactly
    hipLaunchKernelGGL(lconv_kernel, grid, block, 0, stream, x, w1, w2, out);
}